// Round 15
// baseline (226.100 us; speedup 1.0000x reference)
//
#include <hip/hip_runtime.h>
#include <hip/hip_bf16.h>

#define INFV 100000.0f
#define CQK 0.14433756729740643f
#define SQCQK 0.3799178428257963f
#define CB  0.5773502691896258f
#define INV_SQRT96 0.10206207261596577f

typedef short bf16x8 __attribute__((ext_vector_type(8)));
typedef float f32x4 __attribute__((ext_vector_type(4)));

// workspace layout (float offsets)
#define OFF_WT    0          // [384][1152]
#define OFF_WOT   442368     // [960][384]
#define OFF_BU    811008     // [1152]
#define OFF_BM    1328256    // bf16 [12][768*768]  (pre-scaled CB*(z@Wb+bb))
#define OFF_A     4867200    // bf16 [12][768][768] normalized attention
#define OFF_VCT   8406144    // bf16 [12][48][768]  V-concat transposed
#define OFF_PZ    8627328    // bf16 [768 i][32 d][768 j]  pair_z TRANSPOSED
#define OFF_O     18064512   // [768][192]
#define OFF_OPT   18211968   // [768][288] global-frame o_pt
#define OFF_OPAIR 18433152   // [768][384]
#define OFF_ZB    18728064   // 4 floats of zeros (16B)
#define OFF_WC    18728068   // bf16 [48][128] combined z-proj weights
#define OFF_BC    18731140   // float [48]
#define OFF_QC    18731200   // bf16 [12][768][64] q-concat
#define OFF_KC    19026112   // bf16 [12][768][64] k-concat
#define OFF_SQK   19321024   // f32 [12][768] |kp|^2
// total = 19330240 floats = 77.3 MB

static __device__ __forceinline__ unsigned short f2bf(float x) {
  union { __hip_bfloat16 b; unsigned short u; } cv;
  cv.b = __float2bfloat16(x);
  return cv.u;
}
static __device__ __forceinline__ float bf2f(unsigned short b) {
  return __uint_as_float(((unsigned int)b) << 16);
}

// ---------------- kernel T: weight transposes + bias + zero pads + Wc ----------------
__global__ __launch_bounds__(256) void kT(
    const float* __restrict__ Wq, const float* __restrict__ Wkv,
    const float* __restrict__ Wqp, const float* __restrict__ Wkvp,
    const float* __restrict__ Wout,
    const float* __restrict__ bq, const float* __restrict__ bkv,
    const float* __restrict__ bqp, const float* __restrict__ bkvp,
    const float* __restrict__ Wb, const float* __restrict__ bb,
    const float* __restrict__ Wdz, const float* __restrict__ bdz,
    float* __restrict__ WT, float* __restrict__ WoutT, float* __restrict__ bu,
    unsigned short* __restrict__ vcT, float* __restrict__ zb,
    unsigned short* __restrict__ Wc, float* __restrict__ biasc) {
  int tid = blockIdx.x * 256 + threadIdx.x;
  if (tid < 442368) {
    int f = tid / 1152, u = tid % 1152;
    float w;
    if (u < 192)      w = Wq[u * 384 + f];
    else if (u < 576) w = Wkv[(u - 192) * 384 + f];
    else if (u < 720) w = Wqp[(u - 576) * 384 + f];
    else              w = Wkvp[(u - 720) * 384 + f];
    WT[tid] = w;
  } else if (tid < 811008) {
    int r = tid - 442368;
    int f = r / 384, o = r % 384;
    WoutT[r] = Wout[o * 960 + f];
  } else if (tid < 812160) {
    int u = tid - 811008;
    float bv;
    if (u < 192)      bv = bq[u];
    else if (u < 576) bv = bkv[u - 192];
    else if (u < 720) bv = bqp[u - 576];
    else              bv = bkvp[u - 720];
    bu[u] = bv;
  } else if (tid < 849024) {
    int zid = tid - 812160;            // zero vcT pad cols 40..47 per h
    int h = zid / 3072, r = zid % 3072;
    ((unsigned int*)(vcT + h * 36864 + 40 * 768))[r] = 0u;
  } else if (tid < 849028) {
    ((unsigned int*)zb)[tid - 849024] = 0u;
  } else if (tid < 855172) {
    int wid = tid - 849028;
    int n = wid >> 7, k = wid & 127;
    float val = (n < 12) ? CB * Wb[n * 128 + k] : ((n < 44) ? Wdz[(n - 12) * 128 + k] : 0.f);
    Wc[wid] = f2bf(val);
  } else if (tid < 855220) {
    int n = tid - 855172;
    biasc[n] = (n < 12) ? CB * bb[n] : ((n < 44) ? bdz[n - 12] : 0.f);
  }
}

// ---------------- kernel A: s projections + point rotation -> qc/kc/sqk/vcT ----------------
// grid 192, block 384, 4 rows/block
__global__ __launch_bounds__(384) void kA(
    const float* __restrict__ s, const float* __restrict__ rot, const float* __restrict__ trans,
    const float* __restrict__ WT, const float* __restrict__ bu,
    unsigned short* __restrict__ qc, unsigned short* __restrict__ kc,
    float* __restrict__ sqk, unsigned short* __restrict__ vcT) {
  __shared__ float sA[4][384];
  __shared__ float praw[4][576];
  __shared__ float sqp[4][12][4];
  const int t = threadIdx.x;
  const int n0 = blockIdx.x * 4;
  for (int idx = t; idx < 4 * 384; idx += 384) sA[idx / 384][idx % 384] = s[n0 * 384 + idx];
  __syncthreads();

  float acc[3][4];
#pragma unroll
  for (int a = 0; a < 3; a++)
#pragma unroll
    for (int r = 0; r < 4; r++) acc[a][r] = 0.f;
  const int u0 = t, u1 = t + 384, u2 = t + 768;

  for (int f = 0; f < 384; f += 4) {
    float4 sr0 = *(const float4*)&sA[0][f];
    float4 sr1 = *(const float4*)&sA[1][f];
    float4 sr2 = *(const float4*)&sA[2][f];
    float4 sr3 = *(const float4*)&sA[3][f];
#pragma unroll
    for (int ff = 0; ff < 4; ff++) {
      const float* wrow = WT + (size_t)(f + ff) * 1152;
      float w0 = wrow[u0], w1 = wrow[u1], w2 = wrow[u2];
      float v0 = ((const float*)&sr0)[ff];
      float v1 = ((const float*)&sr1)[ff];
      float v2 = ((const float*)&sr2)[ff];
      float v3 = ((const float*)&sr3)[ff];
      acc[0][0] = fmaf(w0, v0, acc[0][0]); acc[0][1] = fmaf(w0, v1, acc[0][1]);
      acc[0][2] = fmaf(w0, v2, acc[0][2]); acc[0][3] = fmaf(w0, v3, acc[0][3]);
      acc[1][0] = fmaf(w1, v0, acc[1][0]); acc[1][1] = fmaf(w1, v1, acc[1][1]);
      acc[1][2] = fmaf(w1, v2, acc[1][2]); acc[1][3] = fmaf(w1, v3, acc[1][3]);
      acc[2][0] = fmaf(w2, v0, acc[2][0]); acc[2][1] = fmaf(w2, v1, acc[2][1]);
      acc[2][2] = fmaf(w2, v2, acc[2][2]); acc[2][3] = fmaf(w2, v3, acc[2][3]);
    }
  }

#pragma unroll
  for (int a = 0; a < 3; a++) {
    int u = t + a * 384;
    float bv = bu[u];
#pragma unroll
    for (int r = 0; r < 4; r++) {
      float val = acc[a][r] + bv;
      int n = n0 + r;
      if (u < 192) {
        int h = u >> 4, c = u & 15;
        qc[((size_t)(h * 768) + n) * 64 + c] = f2bf(SQCQK * val);
      } else if (u < 576) {
        int l2 = u - 192, h = l2 >> 5, rem = l2 & 31;
        if (rem < 16) kc[((size_t)(h * 768) + n) * 64 + rem] = f2bf(SQCQK * val);
        else          vcT[h * 36864 + (rem - 16) * 768 + n] = f2bf(val);
      } else {
        praw[r][u - 576] = val;
      }
    }
  }
  __syncthreads();

  // rotate + translate all points; write hi/lo concat layouts
  for (int task = t; task < 768; task += 384) {
    int r = task / 192, rem = task % 192;
    int h = rem >> 4, pidx = rem & 15;
    int n = n0 + r;
    const float* R = rot + n * 9;
    const float* tr = trans + n * 3;
    float x, y, z;
    if (pidx < 4) {
      int p = h * 4 + pidx;
      x = praw[r][p]; y = praw[r][48 + p]; z = praw[r][96 + p];
    } else {
      int pp = h * 12 + (pidx - 4);
      x = praw[r][144 + pp]; y = praw[r][288 + pp]; z = praw[r][432 + pp];
    }
    float g0 = R[0] * x + R[1] * y + R[2] * z + tr[0];
    float g1 = R[3] * x + R[4] * y + R[5] * z + tr[1];
    float g2 = R[6] * x + R[7] * y + R[8] * z + tr[2];
    if (pidx < 4) {
      unsigned short* base = qc + ((size_t)(h * 768) + n) * 64;
      int d0 = 16 + pidx * 3;
      float g[3] = {g0, g1, g2};
#pragma unroll
      for (int c = 0; c < 3; c++) {
        unsigned short hi = f2bf(g[c]);
        unsigned short lo = f2bf(g[c] - bf2f(hi));
        base[d0 + c] = hi; base[12 + d0 + c] = lo; base[24 + d0 + c] = hi;
      }
    } else if (pidx < 8) {
      unsigned short* base = kc + ((size_t)(h * 768) + n) * 64;
      int d0 = 16 + (pidx - 4) * 3;
      float g[3] = {g0, g1, g2};
#pragma unroll
      for (int c = 0; c < 3; c++) {
        unsigned short hi = f2bf(g[c]);
        unsigned short lo = f2bf(g[c] - bf2f(hi));
        base[d0 + c] = hi; base[12 + d0 + c] = hi; base[24 + d0 + c] = lo;
      }
      sqp[r][h][pidx - 4] = g0 * g0 + g1 * g1 + g2 * g2;
    } else {
      int pv = pidx - 8;
      unsigned short* vb = vcT + h * 36864 + (16 + pv * 3) * 768 + n;
      vb[0] = f2bf(g0); vb[768] = f2bf(g1); vb[1536] = f2bf(g2);
    }
  }
  // zero pads (cols 52..63)
  for (int task = t; task < 576; task += 384) {
    int r = task / 144, rem = task % 144;
    int h = rem / 12, c = rem % 12;
    size_t off = ((size_t)(h * 768) + n0 + r) * 64 + 52 + c;
    qc[off] = 0; kc[off] = 0;
  }
  __syncthreads();
  if (t < 48) {
    int r = t / 12, h = t % 12;
    sqk[h * 768 + n0 + r] = sqp[r][h][0] + sqp[r][h][1] + sqp[r][h][2] + sqp[r][h][3];
  }
}

// ---------------- kernel B7: z -> bm16 + pzT via MFMA (LDS-aliased, VGPR-capped) ----------------
// grid 9216 (one i, 64 j's each), block 256 (4 waves)
// __launch_bounds__(256, 8): force VGPR <= 64 so occupancy is LDS-capped (5 blocks/CU), not VGPR-capped (4)
__global__ __launch_bounds__(256, 8) void kB7(
    const float* __restrict__ z, const unsigned short* __restrict__ Wc,
    const float* __restrict__ biasc,
    unsigned short* __restrict__ bm16, unsigned short* __restrict__ pzT) {
  __shared__ unsigned short zbuf[64 * 136];
  __shared__ unsigned short wL[48][136];
  __shared__ float biasL[48];
  const int t = threadIdx.x;
  const size_t pid0 = (size_t)blockIdx.x * 64;
  const int iRow = blockIdx.x / 12;
  const int j0 = (blockIdx.x % 12) * 64;

  // stage W (48x128 bf16)
  {
    const unsigned int* wsrc = (const unsigned int*)Wc;
#pragma unroll
    for (int it = 0; it < 12; it++) {
      int idx = it * 256 + t;
      int n = idx >> 6, col = (idx & 63) * 2;
      *(unsigned int*)&wL[n][col] = wsrc[idx];
    }
    if (t < 48) biasL[t] = biasc[t];
  }
  // stage z tile (64 rows x 128 fp32 -> bf16), fully coalesced
  const float4* zsrc = (const float4*)(z + pid0 * 128);
#pragma unroll 2
  for (int it = 0; it < 8; it++) {
    int f4 = it * 256 + t;
    float4 v = zsrc[f4];
    int row = f4 >> 5, col = (f4 & 31) * 4;
    unsigned int p0 = (unsigned int)f2bf(v.x) | ((unsigned int)f2bf(v.y) << 16);
    unsigned int p1 = (unsigned int)f2bf(v.z) | ((unsigned int)f2bf(v.w) << 16);
    *(uint2*)&zbuf[row * 136 + col] = make_uint2(p0, p1);
  }
  __syncthreads();   // zL + wL ready

  const int w = t >> 6, l = t & 63;
  const int lr = l & 15, hk = l >> 4;
  f32x4 acc0 = {0.f, 0.f, 0.f, 0.f}, acc1 = acc0, acc2 = acc0;
  const int arow = w * 16 + lr;
#pragma unroll
  for (int kc = 0; kc < 4; kc++) {
    int col = kc * 32 + hk * 8;
    bf16x8 af = *(const bf16x8*)&zbuf[arow * 136 + col];
    bf16x8 b0 = *(const bf16x8*)&wL[lr][col];
    bf16x8 b1 = *(const bf16x8*)&wL[16 + lr][col];
    bf16x8 b2 = *(const bf16x8*)&wL[32 + lr][col];
    acc0 = __builtin_amdgcn_mfma_f32_16x16x32_bf16(af, b0, acc0, 0, 0, 0);
    acc1 = __builtin_amdgcn_mfma_f32_16x16x32_bf16(af, b1, acc1, 0, 0, 0);
    acc2 = __builtin_amdgcn_mfma_f32_16x16x32_bf16(af, b2, acc2, 0, 0, 0);
  }
  __syncthreads();   // all zL reads done -> zbuf reusable as oD

  {
    const float b0f = biasL[lr], b1f = biasL[16 + lr], b2f = biasL[32 + lr];
    int rb = w * 16 + hk * 4;
#pragma unroll
    for (int r = 0; r < 4; r++) {
      zbuf[(rb + r) * 49 + lr]      = f2bf(acc0[r] + b0f);
      zbuf[(rb + r) * 49 + 16 + lr] = f2bf(acc1[r] + b1f);
      zbuf[(rb + r) * 49 + 32 + lr] = f2bf(acc2[r] + b2f);
    }
  }
  __syncthreads();   // oD ready

  // pzT: [i][d][j] — each thread packs 8 j's of one d-row (oD cols 12..43)
  {
    int d = t >> 3, jc = t & 7;
    union { unsigned short u[8]; uint4 v; } pk;
#pragma unroll
    for (int e = 0; e < 8; e++) pk.u[e] = zbuf[(jc * 8 + e) * 49 + 12 + d];
    *(uint4*)(pzT + ((size_t)iRow * 32 + d) * 768 + j0 + jc * 8) = pk.v;
  }
  // bm16: 12 planes x 32 uints (oD cols 0..11)
  for (int idx = t; idx < 384; idx += 256) {
    int h = idx / 32, pr = idx % 32;
    unsigned int u = (unsigned int)zbuf[(2 * pr) * 49 + h] | ((unsigned int)zbuf[(2 * pr + 1) * 49 + h] << 16);
    ((unsigned int*)(bm16 + (size_t)h * 589824 + pid0))[pr] = u;
  }
}

// ---------------- kernel C1M: logits via MFMA + softmax -> A ----------------
// grid 576 (h x 48 i-tiles of 16), block 256 (4 waves)
__global__ __launch_bounds__(256) void kC1M(
    const unsigned short* __restrict__ qc, const unsigned short* __restrict__ kc,
    const float* __restrict__ sqk, const unsigned short* __restrict__ bm16,
    const float* __restrict__ mask, unsigned short* __restrict__ A) {
  __shared__ float lg[16 * 780];
  const int t = threadIdx.x;
  const int h = blockIdx.x % 12, it = blockIdx.x / 12;
  const int i0 = it * 16;
  const int w = t >> 6, l = t & 63;
  const int lr = l & 15, hk = l >> 4;

  const unsigned short* qrow = qc + ((size_t)(h * 768) + i0 + lr) * 64 + hk * 8;
  bf16x8 a0 = *(const bf16x8*)(qrow);
  bf16x8 a1 = *(const bf16x8*)(qrow + 32);
  float miA[4];
#pragma unroll
  for (int r = 0; r < 4; r++) miA[r] = mask[i0 + hk * 4 + r];

  for (int q = 0; q < 12; q++) {
    int j0 = (w * 12 + q) * 16;
    const unsigned short* krow = kc + ((size_t)(h * 768) + j0 + lr) * 64 + hk * 8;
    bf16x8 b0 = *(const bf16x8*)(krow);
    bf16x8 b1 = *(const bf16x8*)(krow + 32);
    f32x4 acc = {0.f, 0.f, 0.f, 0.f};
    acc = __builtin_amdgcn_mfma_f32_16x16x32_bf16(a0, b0, acc, 0, 0, 0);
    acc = __builtin_amdgcn_mfma_f32_16x16x32_bf16(a1, b1, acc, 0, 0, 0);
    int j = j0 + lr;
    float skj = 0.5f * sqk[h * 768 + j];
    float mj = mask[j];
    const unsigned short* bmc = bm16 + (size_t)h * 589824 + (size_t)(i0 + hk * 4) * 768 + j;
#pragma unroll
    for (int r = 0; r < 4; r++) {
      int ii = hk * 4 + r;
      float bsc = bf2f(bmc[r * 768]);
      lg[ii * 780 + j] = acc[r] - skj + bsc + INFV * (miA[r] * mj - 1.0f);
    }
  }
  __syncthreads();

  const int ln = l;
#pragma unroll
  for (int rr = 0; rr < 4; rr++) {
    int row = w * 4 + rr;
    float* rowp = lg + row * 780;
    float m = -3.0e38f;
#pragma unroll
    for (int kq = 0; kq < 12; kq++) m = fmaxf(m, rowp[ln + kq * 64]);
#pragma unroll
    for (int sh = 1; sh < 64; sh <<= 1) m = fmaxf(m, __shfl_xor(m, sh));
    float ssum = 0.f;
#pragma unroll
    for (int kq = 0; kq < 12; kq++) {
      float e = __expf(rowp[ln + kq * 64] - m);
      rowp[ln + kq * 64] = e;          // store exp in place (no recompute below)
      ssum += e;
    }
#pragma unroll
    for (int sh = 1; sh < 64; sh <<= 1) ssum += __shfl_xor(ssum, sh);
    float iv = 1.0f / ssum;
    unsigned int* arow = (unsigned int*)(A + (size_t)h * 589824 + (size_t)(i0 + row) * 768);
#pragma unroll
    for (int kq = 0; kq < 6; kq++) {
      int jp = ln + kq * 64;
      float e0 = rowp[2 * jp] * iv;
      float e1 = rowp[2 * jp + 1] * iv;
      arow[jp] = (unsigned int)f2bf(e0) | ((unsigned int)f2bf(e1) << 16);
    }
  }
}

// ---------------- kernel C23: merged o/o_pt (blocks 0..575) + o_pair (blocks 576..1343) ----------------
__global__ __launch_bounds__(256) void kC23(
    const unsigned short* __restrict__ A, const unsigned short* __restrict__ vcT,
    const unsigned short* __restrict__ pzT, const unsigned short* __restrict__ zb,
    float* __restrict__ o_out, float* __restrict__ opt_out, float* __restrict__ opair_out) {
  __shared__ float red[4][16][49];
  const int t = threadIdx.x;
  const int w = t >> 6, l = t & 63;
  const int lr = l & 15, lk = (l >> 4) * 8;

  if (blockIdx.x < 576) {
    // o + o_pt: h x 48 i-tiles of 16, 4 waves split K
    const int h = blockIdx.x % 12, it = blockIdx.x / 12;
    const int i0 = it * 16;
    f32x4 acc0 = {0.f, 0.f, 0.f, 0.f}, acc1 = acc0, acc2 = acc0;
    const unsigned short* ab = A + (size_t)h * 589824 + (size_t)(i0 + lr) * 768 + lk;
    const unsigned short* bb = vcT + h * 36864 + lr * 768 + lk;
#pragma unroll
    for (int kc = 0; kc < 6; kc++) {
      int k0 = w * 192 + kc * 32;
      bf16x8 avf = *(const bf16x8*)(ab + k0);
      bf16x8 b0 = *(const bf16x8*)(bb + k0);
      bf16x8 b1 = *(const bf16x8*)(bb + 16 * 768 + k0);
      bf16x8 b2 = *(const bf16x8*)(bb + 32 * 768 + k0);
      acc0 = __builtin_amdgcn_mfma_f32_16x16x32_bf16(avf, b0, acc0, 0, 0, 0);
      acc1 = __builtin_amdgcn_mfma_f32_16x16x32_bf16(avf, b1, acc1, 0, 0, 0);
      acc2 = __builtin_amdgcn_mfma_f32_16x16x32_bf16(avf, b2, acc2, 0, 0, 0);
    }
    const int rb = (l >> 4) * 4;
#pragma unroll
    for (int r = 0; r < 4; r++) {
      red[w][rb + r][lr] = acc0[r];
      red[w][rb + r][16 + lr] = acc1[r];
      red[w][rb + r][32 + lr] = acc2[r];
    }
    __syncthreads();
    for (int idx = t; idx < 768; idx += 256) {
      int row = idx / 48, c = idx % 48;
      float sv = red[0][row][c] + red[1][row][c] + red[2][row][c] + red[3][row][c];
      int gr = i0 + row;
      if (c < 16)      o_out[gr * 192 + h * 16 + c] = sv;
      else if (c < 40) opt_out[gr * 288 + h * 24 + (c - 16)] = sv;
    }
  } else {
    // o_pair: one i per block, 4 waves split K
    const int i = blockIdx.x - 576;
    f32x4 acc0 = {0.f, 0.f, 0.f, 0.f}, acc1 = acc0;
    const unsigned short* abase = (lr < 12) ? (A + (size_t)lr * 589824 + i * 768 + lk) : zb;
    const int astep = (lr < 12) ? 1 : 0;
    const unsigned short* pz0 = pzT + ((size_t)i * 32 + lr) * 768 + lk;
    const unsigned short* pz1 = pzT + ((size_t)i * 32 + 16 + lr) * 768 + lk;
#pragma unroll
    for (int kc = 0; kc < 6; kc++) {
      int k0 = w * 192 + kc * 32;
      bf16x8 avf = *(const bf16x8*)(abase + astep * k0);
      bf16x8 b0 = *(const bf16x8*)(pz0 + k0);
      bf16x8 b1 = *(const bf16x8*)(pz1 + k0);
      acc0 = __builtin_amdgcn_mfma_f32_16x16x32_bf16(avf, b0, acc0, 0, 0, 0);
      acc1 = __builtin_amdgcn_mfma_f32_16x16x32_bf16(avf, b1, acc1, 0, 0, 0);
    }
#pragma unroll
    for (int r = 0; r < 4; r++) {
      red[w][(l >> 4) * 4 + r][lr] = acc0[r];
      red[w][(l >> 4) * 4 + r][16 + lr] = acc1[r];
    }
    __syncthreads();
    for (int idx = t; idx < 512; idx += 256) {
      int row = idx >> 5, col = idx & 31;
      if (row < 12) {
        float sv = red[0][row][col] + red[1][row][col] + red[2][row][col] + red[3][row][col];
        opair_out[i * 384 + row * 32 + col] = sv;
      }
    }
  }
}

// ---------------- kernel D: localize, dists, l1_out, final GEMM ----------------
__global__ __launch_bounds__(512) void kD(
    const float* __restrict__ o_in, const float* __restrict__ opt_in, const float* __restrict__ opair_in,
    const float* __restrict__ rot, const float* __restrict__ trans,
    const float* __restrict__ l1f, const float* __restrict__ Wl1,
    const float* __restrict__ WoutT, const float* __restrict__ bout,
    const float* __restrict__ s_org, float* __restrict__ out) {
  __shared__ float feats[4][960];
  __shared__ float part[2][256][6];
  const int t = threadIdx.x;
  const int n0 = blockIdx.x * 4;

  for (int idx = t; idx < 768; idx += 512) feats[idx / 192][idx % 192] = o_in[n0 * 192 + idx];
  for (int idx = t; idx < 1536; idx += 512) feats[idx / 384][576 + idx % 384] = opair_in[n0 * 384 + idx];
  if (t < 384) {
    int r = t / 96, p = t % 96, n = n0 + r;
    float x = opt_in[n * 288 + p * 3 + 0];
    float y = opt_in[n * 288 + p * 3 + 1];
    float zc = opt_in[n * 288 + p * 3 + 2];
    const float* R = rot + n * 9;
    const float* tr = trans + n * 3;
    float dx = x - tr[0], dy = y - tr[1], dz = zc - tr[2];
    float l0 = R[0] * dx + R[3] * dy + R[6] * dz;
    float l1 = R[1] * dx + R[4] * dy + R[7] * dz;
    float l2 = R[2] * dx + R[5] * dy + R[8] * dz;
    feats[r][192 + p] = l0;
    feats[r][288 + p] = l1;
    feats[r][384 + p] = l2;
    feats[r][480 + p] = sqrtf(l0 * l0 + l1 * l1 + l2 * l2 + 1e-8f);
  } else if (t < 432) {
    int tt = t - 384, r = tt / 12, lq = tt % 12, n = n0 + r;
    int oo = lq / 3, cc = lq % 3;
    float acc = 0.f;
    for (int i = 0; i < 96; i++) acc = fmaf(opt_in[n * 288 + i * 3 + cc], Wl1[i * 4 + oo], acc);
    out[294912 + n * 12 + lq] = l1f[n * 12 + lq] + acc * INV_SQRT96;
  }
  __syncthreads();

  const int fh = t >> 8, tt = t & 255;
  const int o0 = tt & 127, rp = tt >> 7;
  float acc[3][2] = {{0.f, 0.f}, {0.f, 0.f}, {0.f, 0.f}};
  for (int f = fh * 480; f < fh * 480 + 480; f++) {
    float w0 = WoutT[f * 384 + o0];
    float w1 = WoutT[f * 384 + o0 + 128];
    float w2 = WoutT[f * 384 + o0 + 256];
    float s0 = feats[rp * 2][f], s1 = feats[rp * 2 + 1][f];
    acc[0][0] = fmaf(w0, s0, acc[0][0]); acc[0][1] = fmaf(w0, s1, acc[0][1]);
    acc[1][0] = fmaf(w1, s0, acc[1][0]); acc[1][1] = fmaf(w1, s1, acc[1][1]);
    acc[2][0] = fmaf(w2, s0, acc[2][0]); acc[2][1] = fmaf(w2, s1, acc[2][1]);
  }
#pragma unroll
  for (int kq = 0; kq < 3; kq++)
#pragma unroll
    for (int r = 0; r < 2; r++) part[fh][tt][kq * 2 + r] = acc[kq][r];
  __syncthreads();
  if (t < 256) {
    const int ob = t & 127, rb = t >> 7;
#pragma unroll
    for (int kq = 0; kq < 3; kq++) {
      int o = ob + kq * 128;
#pragma unroll
      for (int r = 0; r < 2; r++) {
        int n = n0 + rb * 2 + r;
        float v = part[0][t][kq * 2 + r] + part[1][t][kq * 2 + r] + bout[o] + s_org[n * 384 + o];
        out[n * 384 + o] = v;
      }
    }
  }
}

extern "C" void kernel_launch(void* const* d_in, const int* in_sizes, int n_in,
                              void* d_out, int out_size, void* d_ws, size_t ws_size,
                              hipStream_t stream) {
  (void)in_sizes; (void)n_in; (void)out_size; (void)ws_size;
  const float* s     = (const float*)d_in[0];
  const float* z     = (const float*)d_in[1];
  const float* l1f   = (const float*)d_in[2];
  const float* rot   = (const float*)d_in[3];
  const float* trans = (const float*)d_in[4];
  const float* mask  = (const float*)d_in[5];
  const float* Wq    = (const float*)d_in[6];
  const float* bq    = (const float*)d_in[7];
  const float* Wkv   = (const float*)d_in[8];
  const float* bkv   = (const float*)d_in[9];
  const float* Wqp   = (const float*)d_in[10];
  const float* bqp   = (const float*)d_in[11];
  const float* Wkvp  = (const float*)d_in[12];
  const float* bkvp  = (const float*)d_in[13];
  const float* Wb    = (const float*)d_in[14];
  const float* bb    = (const float*)d_in[15];
  const float* Wdz   = (const float*)d_in[16];
  const float* bdz   = (const float*)d_in[17];
  const float* Wout  = (const float*)d_in[18];
  const float* bout  = (const float*)d_in[19];
  const float* Wl1   = (const float*)d_in[20];
  float* out = (float*)d_out;
  float* ws  = (float*)d_ws;

  float* WT    = ws + OFF_WT;
  float* WoutT = ws + OFF_WOT;
  float* bu    = ws + OFF_BU;
  unsigned short* bm16 = (unsigned short*)(ws + OFF_BM);
  unsigned short* Ab   = (unsigned short*)(ws + OFF_A);
  unsigned short* vcT  = (unsigned short*)(ws + OFF_VCT);
  unsigned short* pzTb = (unsigned short*)(ws + OFF_PZ);
  float* ob    = ws + OFF_O;
  float* optb  = ws + OFF_OPT;
  float* opairb= ws + OFF_OPAIR;
  float* zbf   = ws + OFF_ZB;
  unsigned short* Wc = (unsigned short*)(ws + OFF_WC);
  float* biasc = ws + OFF_BC;
  unsigned short* qcb = (unsigned short*)(ws + OFF_QC);
  unsigned short* kcb = (unsigned short*)(ws + OFF_KC);
  float* sqkb = ws + OFF_SQK;

  kT<<<3342, 256, 0, stream>>>(Wq, Wkv, Wqp, Wkvp, Wout, bq, bkv, bqp, bkvp,
                               Wb, bb, Wdz, bdz,
                               WT, WoutT, bu, vcT, zbf, Wc, biasc);
  kA<<<192, 384, 0, stream>>>(s, rot, trans, WT, bu, qcb, kcb, sqkb, vcT);
  kB7<<<9216, 256, 0, stream>>>(z, Wc, biasc, bm16, pzTb);
  kC1M<<<576, 256, 0, stream>>>(qcb, kcb, sqkb, bm16, mask, Ab);
  kC23<<<1344, 256, 0, stream>>>(Ab, vcT, pzTb, (const unsigned short*)zbf, ob, optb, opairb);
  kD<<<192, 512, 0, stream>>>(ob, optb, opairb, rot, trans, l1f, Wl1, WoutT, bout, s, out);
}

// Round 17
// 224.020 us; speedup vs baseline: 1.0093x; 1.0093x over previous
//
#include <hip/hip_runtime.h>
#include <hip/hip_bf16.h>

#define INFV 100000.0f
#define CQK 0.14433756729740643f
#define SQCQK 0.3799178428257963f
#define CB  0.5773502691896258f
#define INV_SQRT96 0.10206207261596577f

typedef short bf16x8 __attribute__((ext_vector_type(8)));
typedef float f32x4 __attribute__((ext_vector_type(4)));

// workspace layout (float offsets)
#define OFF_WT    0          // [384][1152]
#define OFF_WOT   442368     // [960][384]
#define OFF_BU    811008     // [1152]
#define OFF_BM    1328256    // bf16 [12][768*768]  (pre-scaled CB*(z@Wb+bb))
#define OFF_A     4867200    // bf16 [12][768][768] normalized attention
#define OFF_VCT   8406144    // bf16 [12][48][768]  V-concat transposed
#define OFF_PZ    8627328    // bf16 [768 i][32 d][768 j]  pair_z TRANSPOSED
#define OFF_O     18064512   // [768][192]
#define OFF_OPT   18211968   // [768][288] global-frame o_pt
#define OFF_OPAIR 18433152   // [768][384]
#define OFF_ZB    18728064   // 4 floats of zeros (16B)
#define OFF_WC    18728068   // bf16 [48][128] combined z-proj weights
#define OFF_BC    18731140   // float [48]
#define OFF_QC    18731200   // bf16 [12][768][64] q-concat
#define OFF_KC    19026112   // bf16 [12][768][64] k-concat
#define OFF_SQK   19321024   // f32 [12][768] |kp|^2
// total = 19330240 floats = 77.3 MB

static __device__ __forceinline__ unsigned short f2bf(float x) {
  union { __hip_bfloat16 b; unsigned short u; } cv;
  cv.b = __float2bfloat16(x);
  return cv.u;
}
static __device__ __forceinline__ float bf2f(unsigned short b) {
  return __uint_as_float(((unsigned int)b) << 16);
}

// ---------------- kernel T: weight transposes + bias + zero pads + Wc ----------------
__global__ __launch_bounds__(256) void kT(
    const float* __restrict__ Wq, const float* __restrict__ Wkv,
    const float* __restrict__ Wqp, const float* __restrict__ Wkvp,
    const float* __restrict__ Wout,
    const float* __restrict__ bq, const float* __restrict__ bkv,
    const float* __restrict__ bqp, const float* __restrict__ bkvp,
    const float* __restrict__ Wb, const float* __restrict__ bb,
    const float* __restrict__ Wdz, const float* __restrict__ bdz,
    float* __restrict__ WT, float* __restrict__ WoutT, float* __restrict__ bu,
    unsigned short* __restrict__ vcT, float* __restrict__ zb,
    unsigned short* __restrict__ Wc, float* __restrict__ biasc) {
  int tid = blockIdx.x * 256 + threadIdx.x;
  if (tid < 442368) {
    int f = tid / 1152, u = tid % 1152;
    float w;
    if (u < 192)      w = Wq[u * 384 + f];
    else if (u < 576) w = Wkv[(u - 192) * 384 + f];
    else if (u < 720) w = Wqp[(u - 576) * 384 + f];
    else              w = Wkvp[(u - 720) * 384 + f];
    WT[tid] = w;
  } else if (tid < 811008) {
    int r = tid - 442368;
    int f = r / 384, o = r % 384;
    WoutT[r] = Wout[o * 960 + f];
  } else if (tid < 812160) {
    int u = tid - 811008;
    float bv;
    if (u < 192)      bv = bq[u];
    else if (u < 576) bv = bkv[u - 192];
    else if (u < 720) bv = bqp[u - 576];
    else              bv = bkvp[u - 720];
    bu[u] = bv;
  } else if (tid < 849024) {
    int zid = tid - 812160;            // zero vcT pad cols 40..47 per h
    int h = zid / 3072, r = zid % 3072;
    ((unsigned int*)(vcT + h * 36864 + 40 * 768))[r] = 0u;
  } else if (tid < 849028) {
    ((unsigned int*)zb)[tid - 849024] = 0u;
  } else if (tid < 855172) {
    int wid = tid - 849028;
    int n = wid >> 7, k = wid & 127;
    float val = (n < 12) ? CB * Wb[n * 128 + k] : ((n < 44) ? Wdz[(n - 12) * 128 + k] : 0.f);
    Wc[wid] = f2bf(val);
  } else if (tid < 855220) {
    int n = tid - 855172;
    biasc[n] = (n < 12) ? CB * bb[n] : ((n < 44) ? bdz[n - 12] : 0.f);
  }
}

// ---------------- kernel A: s projections + point rotation -> qc/kc/sqk/vcT ----------------
// grid 192, block 384, 4 rows/block
__global__ __launch_bounds__(384) void kA(
    const float* __restrict__ s, const float* __restrict__ rot, const float* __restrict__ trans,
    const float* __restrict__ WT, const float* __restrict__ bu,
    unsigned short* __restrict__ qc, unsigned short* __restrict__ kc,
    float* __restrict__ sqk, unsigned short* __restrict__ vcT) {
  __shared__ float sA[4][384];
  __shared__ float praw[4][576];
  __shared__ float sqp[4][12][4];
  const int t = threadIdx.x;
  const int n0 = blockIdx.x * 4;
  for (int idx = t; idx < 4 * 384; idx += 384) sA[idx / 384][idx % 384] = s[n0 * 384 + idx];
  __syncthreads();

  float acc[3][4];
#pragma unroll
  for (int a = 0; a < 3; a++)
#pragma unroll
    for (int r = 0; r < 4; r++) acc[a][r] = 0.f;
  const int u0 = t, u1 = t + 384, u2 = t + 768;

  for (int f = 0; f < 384; f += 4) {
    float4 sr0 = *(const float4*)&sA[0][f];
    float4 sr1 = *(const float4*)&sA[1][f];
    float4 sr2 = *(const float4*)&sA[2][f];
    float4 sr3 = *(const float4*)&sA[3][f];
#pragma unroll
    for (int ff = 0; ff < 4; ff++) {
      const float* wrow = WT + (size_t)(f + ff) * 1152;
      float w0 = wrow[u0], w1 = wrow[u1], w2 = wrow[u2];
      float v0 = ((const float*)&sr0)[ff];
      float v1 = ((const float*)&sr1)[ff];
      float v2 = ((const float*)&sr2)[ff];
      float v3 = ((const float*)&sr3)[ff];
      acc[0][0] = fmaf(w0, v0, acc[0][0]); acc[0][1] = fmaf(w0, v1, acc[0][1]);
      acc[0][2] = fmaf(w0, v2, acc[0][2]); acc[0][3] = fmaf(w0, v3, acc[0][3]);
      acc[1][0] = fmaf(w1, v0, acc[1][0]); acc[1][1] = fmaf(w1, v1, acc[1][1]);
      acc[1][2] = fmaf(w1, v2, acc[1][2]); acc[1][3] = fmaf(w1, v3, acc[1][3]);
      acc[2][0] = fmaf(w2, v0, acc[2][0]); acc[2][1] = fmaf(w2, v1, acc[2][1]);
      acc[2][2] = fmaf(w2, v2, acc[2][2]); acc[2][3] = fmaf(w2, v3, acc[2][3]);
    }
  }

#pragma unroll
  for (int a = 0; a < 3; a++) {
    int u = t + a * 384;
    float bv = bu[u];
#pragma unroll
    for (int r = 0; r < 4; r++) {
      float val = acc[a][r] + bv;
      int n = n0 + r;
      if (u < 192) {
        int h = u >> 4, c = u & 15;
        qc[((size_t)(h * 768) + n) * 64 + c] = f2bf(SQCQK * val);
      } else if (u < 576) {
        int l2 = u - 192, h = l2 >> 5, rem = l2 & 31;
        if (rem < 16) kc[((size_t)(h * 768) + n) * 64 + rem] = f2bf(SQCQK * val);
        else          vcT[h * 36864 + (rem - 16) * 768 + n] = f2bf(val);
      } else {
        praw[r][u - 576] = val;
      }
    }
  }
  __syncthreads();

  // rotate + translate all points; write hi/lo concat layouts
  for (int task = t; task < 768; task += 384) {
    int r = task / 192, rem = task % 192;
    int h = rem >> 4, pidx = rem & 15;
    int n = n0 + r;
    const float* R = rot + n * 9;
    const float* tr = trans + n * 3;
    float x, y, z;
    if (pidx < 4) {
      int p = h * 4 + pidx;
      x = praw[r][p]; y = praw[r][48 + p]; z = praw[r][96 + p];
    } else {
      int pp = h * 12 + (pidx - 4);
      x = praw[r][144 + pp]; y = praw[r][288 + pp]; z = praw[r][432 + pp];
    }
    float g0 = R[0] * x + R[1] * y + R[2] * z + tr[0];
    float g1 = R[3] * x + R[4] * y + R[5] * z + tr[1];
    float g2 = R[6] * x + R[7] * y + R[8] * z + tr[2];
    if (pidx < 4) {
      unsigned short* base = qc + ((size_t)(h * 768) + n) * 64;
      int d0 = 16 + pidx * 3;
      float g[3] = {g0, g1, g2};
#pragma unroll
      for (int c = 0; c < 3; c++) {
        unsigned short hi = f2bf(g[c]);
        unsigned short lo = f2bf(g[c] - bf2f(hi));
        base[d0 + c] = hi; base[12 + d0 + c] = lo; base[24 + d0 + c] = hi;
      }
    } else if (pidx < 8) {
      unsigned short* base = kc + ((size_t)(h * 768) + n) * 64;
      int d0 = 16 + (pidx - 4) * 3;
      float g[3] = {g0, g1, g2};
#pragma unroll
      for (int c = 0; c < 3; c++) {
        unsigned short hi = f2bf(g[c]);
        unsigned short lo = f2bf(g[c] - bf2f(hi));
        base[d0 + c] = hi; base[12 + d0 + c] = hi; base[24 + d0 + c] = lo;
      }
      sqp[r][h][pidx - 4] = g0 * g0 + g1 * g1 + g2 * g2;
    } else {
      int pv = pidx - 8;
      unsigned short* vb = vcT + h * 36864 + (16 + pv * 3) * 768 + n;
      vb[0] = f2bf(g0); vb[768] = f2bf(g1); vb[1536] = f2bf(g2);
    }
  }
  // zero pads (cols 52..63)
  for (int task = t; task < 576; task += 384) {
    int r = task / 144, rem = task % 144;
    int h = rem / 12, c = rem % 12;
    size_t off = ((size_t)(h * 768) + n0 + r) * 64 + 52 + c;
    qc[off] = 0; kc[off] = 0;
  }
  __syncthreads();
  if (t < 48) {
    int r = t / 12, h = t % 12;
    sqk[h * 768 + n0 + r] = sqp[r][h][0] + sqp[r][h][1] + sqp[r][h][2] + sqp[r][h][3];
  }
}

// ---------------- kernel B7: z -> bm16 + pzT via MFMA (LDS-aliased, 30.4 KB) ----------------
// grid 9216 (one i, 64 j's each), block 256 (4 waves)
__global__ __launch_bounds__(256) void kB7(
    const float* __restrict__ z, const unsigned short* __restrict__ Wc,
    const float* __restrict__ biasc,
    unsigned short* __restrict__ bm16, unsigned short* __restrict__ pzT) {
  __shared__ unsigned short zbuf[64 * 136];
  __shared__ unsigned short wL[48][136];
  __shared__ float biasL[48];
  const int t = threadIdx.x;
  const size_t pid0 = (size_t)blockIdx.x * 64;
  const int iRow = blockIdx.x / 12;
  const int j0 = (blockIdx.x % 12) * 64;

  // stage W (48x128 bf16)
  {
    const unsigned int* wsrc = (const unsigned int*)Wc;
#pragma unroll
    for (int it = 0; it < 12; it++) {
      int idx = it * 256 + t;
      int n = idx >> 6, col = (idx & 63) * 2;
      *(unsigned int*)&wL[n][col] = wsrc[idx];
    }
    if (t < 48) biasL[t] = biasc[t];
  }
  // stage z tile (64 rows x 128 fp32 -> bf16), fully coalesced
  const float4* zsrc = (const float4*)(z + pid0 * 128);
#pragma unroll
  for (int it = 0; it < 8; it++) {
    int f4 = it * 256 + t;
    float4 v = zsrc[f4];
    int row = f4 >> 5, col = (f4 & 31) * 4;
    unsigned int p0 = (unsigned int)f2bf(v.x) | ((unsigned int)f2bf(v.y) << 16);
    unsigned int p1 = (unsigned int)f2bf(v.z) | ((unsigned int)f2bf(v.w) << 16);
    *(uint2*)&zbuf[row * 136 + col] = make_uint2(p0, p1);
  }
  __syncthreads();   // zL + wL ready

  const int w = t >> 6, l = t & 63;
  const int lr = l & 15, hk = l >> 4;
  f32x4 acc0 = {0.f, 0.f, 0.f, 0.f}, acc1 = acc0, acc2 = acc0;
  const int arow = w * 16 + lr;
#pragma unroll
  for (int kc = 0; kc < 4; kc++) {
    int col = kc * 32 + hk * 8;
    bf16x8 af = *(const bf16x8*)&zbuf[arow * 136 + col];
    bf16x8 b0 = *(const bf16x8*)&wL[lr][col];
    bf16x8 b1 = *(const bf16x8*)&wL[16 + lr][col];
    bf16x8 b2 = *(const bf16x8*)&wL[32 + lr][col];
    acc0 = __builtin_amdgcn_mfma_f32_16x16x32_bf16(af, b0, acc0, 0, 0, 0);
    acc1 = __builtin_amdgcn_mfma_f32_16x16x32_bf16(af, b1, acc1, 0, 0, 0);
    acc2 = __builtin_amdgcn_mfma_f32_16x16x32_bf16(af, b2, acc2, 0, 0, 0);
  }
  __syncthreads();   // all zL reads done -> zbuf reusable as oD

  {
    const float b0f = biasL[lr], b1f = biasL[16 + lr], b2f = biasL[32 + lr];
    int rb = w * 16 + hk * 4;
#pragma unroll
    for (int r = 0; r < 4; r++) {
      zbuf[(rb + r) * 49 + lr]      = f2bf(acc0[r] + b0f);
      zbuf[(rb + r) * 49 + 16 + lr] = f2bf(acc1[r] + b1f);
      zbuf[(rb + r) * 49 + 32 + lr] = f2bf(acc2[r] + b2f);
    }
  }
  __syncthreads();   // oD ready

  // pzT: [i][d][j] — each thread packs 8 j's of one d-row (oD cols 12..43)
  {
    int d = t >> 3, jc = t & 7;
    union { unsigned short u[8]; uint4 v; } pk;
#pragma unroll
    for (int e = 0; e < 8; e++) pk.u[e] = zbuf[(jc * 8 + e) * 49 + 12 + d];
    *(uint4*)(pzT + ((size_t)iRow * 32 + d) * 768 + j0 + jc * 8) = pk.v;
  }
  // bm16: 12 planes x 32 uints (oD cols 0..11)
  for (int idx = t; idx < 384; idx += 256) {
    int h = idx / 32, pr = idx % 32;
    unsigned int u = (unsigned int)zbuf[(2 * pr) * 49 + h] | ((unsigned int)zbuf[(2 * pr + 1) * 49 + h] << 16);
    ((unsigned int*)(bm16 + (size_t)h * 589824 + pid0))[pr] = u;
  }
}

// ---------------- kernel C1M: logits via MFMA + softmax -> A ----------------
// grid 576 (h x 48 i-tiles of 16), block 256 (4 waves)
__global__ __launch_bounds__(256) void kC1M(
    const unsigned short* __restrict__ qc, const unsigned short* __restrict__ kc,
    const float* __restrict__ sqk, const unsigned short* __restrict__ bm16,
    const float* __restrict__ mask, unsigned short* __restrict__ A) {
  __shared__ float lg[16 * 780];
  const int t = threadIdx.x;
  const int h = blockIdx.x % 12, it = blockIdx.x / 12;
  const int i0 = it * 16;
  const int w = t >> 6, l = t & 63;
  const int lr = l & 15, hk = l >> 4;

  const unsigned short* qrow = qc + ((size_t)(h * 768) + i0 + lr) * 64 + hk * 8;
  bf16x8 a0 = *(const bf16x8*)(qrow);
  bf16x8 a1 = *(const bf16x8*)(qrow + 32);
  float miA[4];
#pragma unroll
  for (int r = 0; r < 4; r++) miA[r] = mask[i0 + hk * 4 + r];

  for (int q = 0; q < 12; q++) {
    int j0 = (w * 12 + q) * 16;
    const unsigned short* krow = kc + ((size_t)(h * 768) + j0 + lr) * 64 + hk * 8;
    bf16x8 b0 = *(const bf16x8*)(krow);
    bf16x8 b1 = *(const bf16x8*)(krow + 32);
    f32x4 acc = {0.f, 0.f, 0.f, 0.f};
    acc = __builtin_amdgcn_mfma_f32_16x16x32_bf16(a0, b0, acc, 0, 0, 0);
    acc = __builtin_amdgcn_mfma_f32_16x16x32_bf16(a1, b1, acc, 0, 0, 0);
    int j = j0 + lr;
    float skj = 0.5f * sqk[h * 768 + j];
    float mj = mask[j];
    const unsigned short* bmc = bm16 + (size_t)h * 589824 + (size_t)(i0 + hk * 4) * 768 + j;
#pragma unroll
    for (int r = 0; r < 4; r++) {
      int ii = hk * 4 + r;
      float bsc = bf2f(bmc[r * 768]);
      lg[ii * 780 + j] = acc[r] - skj + bsc + INFV * (miA[r] * mj - 1.0f);
    }
  }
  __syncthreads();

  const int ln = l;
#pragma unroll
  for (int rr = 0; rr < 4; rr++) {
    int row = w * 4 + rr;
    float* rowp = lg + row * 780;
    float m = -3.0e38f;
#pragma unroll
    for (int kq = 0; kq < 12; kq++) m = fmaxf(m, rowp[ln + kq * 64]);
#pragma unroll
    for (int sh = 1; sh < 64; sh <<= 1) m = fmaxf(m, __shfl_xor(m, sh));
    float ssum = 0.f;
#pragma unroll
    for (int kq = 0; kq < 12; kq++) {
      float e = __expf(rowp[ln + kq * 64] - m);
      rowp[ln + kq * 64] = e;
      ssum += e;
    }
#pragma unroll
    for (int sh = 1; sh < 64; sh <<= 1) ssum += __shfl_xor(ssum, sh);
    float iv = 1.0f / ssum;
    unsigned int* arow = (unsigned int*)(A + (size_t)h * 589824 + (size_t)(i0 + row) * 768);
#pragma unroll
    for (int kq = 0; kq < 6; kq++) {
      int jp = ln + kq * 64;
      float e0 = rowp[2 * jp] * iv;
      float e1 = rowp[2 * jp + 1] * iv;
      arow[jp] = (unsigned int)f2bf(e0) | ((unsigned int)f2bf(e1) << 16);
    }
  }
}

// ---------------- kernel C23b: merged o/o_pt + o_pair, A staged in LDS (XOR-swizzled) ----------------
// write: byte = row*1536 + ((col*4) ^ ((row&7)<<4)); read XORs the FULL in-row offset.
__global__ __launch_bounds__(256) void kC23b(
    const unsigned short* __restrict__ A, const unsigned short* __restrict__ vcT,
    const unsigned short* __restrict__ pzT,
    float* __restrict__ o_out, float* __restrict__ opt_out, float* __restrict__ opair_out) {
  __shared__ unsigned short aL[16 * 768];   // swizzled A tile; red aliased after MFMA
  float* red = (float*)aL;
  const int t = threadIdx.x;
  const int w = t >> 6, l = t & 63;
  const int lr = l & 15, lk = (l >> 4) * 8;

  if (blockIdx.x < 576) {
    const int h = blockIdx.x % 12, it = blockIdx.x / 12;
    const int i0 = it * 16;
    {
      const unsigned int* asrc = (const unsigned int*)(A + (size_t)h * 589824 + (size_t)i0 * 768);
#pragma unroll
      for (int itr = 0; itr < 24; itr++) {
        int idx = itr * 256 + t;           // 16*384 = 6144 uints
        int r = idx / 384, c = idx % 384;
        unsigned int byteoff = (unsigned int)(r * 1536) + (((unsigned int)(c * 4)) ^ (((unsigned int)(r & 7)) << 4));
        *(unsigned int*)((char*)aL + byteoff) = asrc[(size_t)r * 384 + c];
      }
    }
    __syncthreads();

    f32x4 acc0 = {0.f, 0.f, 0.f, 0.f}, acc1 = acc0, acc2 = acc0;
    const unsigned int rowbase = (unsigned int)(lr * 1536);
    const unsigned int xorv = ((unsigned int)(lr & 7)) << 4;
    const unsigned int lk2 = (unsigned int)(lk * 2);
    const unsigned short* bb = vcT + h * 36864 + lr * 768 + lk;
#pragma unroll
    for (int kc = 0; kc < 6; kc++) {
      int k0 = w * 192 + kc * 32;
      unsigned int off = rowbase + (((lk2 + (unsigned int)(k0 * 2))) ^ xorv);
      bf16x8 avf = *(const bf16x8*)((const char*)aL + off);
      bf16x8 b0 = *(const bf16x8*)(bb + k0);
      bf16x8 b1 = *(const bf16x8*)(bb + 16 * 768 + k0);
      bf16x8 b2 = *(const bf16x8*)(bb + 32 * 768 + k0);
      acc0 = __builtin_amdgcn_mfma_f32_16x16x32_bf16(avf, b0, acc0, 0, 0, 0);
      acc1 = __builtin_amdgcn_mfma_f32_16x16x32_bf16(avf, b1, acc1, 0, 0, 0);
      acc2 = __builtin_amdgcn_mfma_f32_16x16x32_bf16(avf, b2, acc2, 0, 0, 0);
    }
    __syncthreads();   // aL reads done -> reuse as red

    const int rb = (l >> 4) * 4;
#pragma unroll
    for (int r = 0; r < 4; r++) {
      red[(w * 16 + rb + r) * 49 + lr] = acc0[r];
      red[(w * 16 + rb + r) * 49 + 16 + lr] = acc1[r];
      red[(w * 16 + rb + r) * 49 + 32 + lr] = acc2[r];
    }
    __syncthreads();
    for (int idx = t; idx < 768; idx += 256) {
      int row = idx / 48, c = idx % 48;
      float sv = red[(0 * 16 + row) * 49 + c] + red[(1 * 16 + row) * 49 + c] +
                 red[(2 * 16 + row) * 49 + c] + red[(3 * 16 + row) * 49 + c];
      int gr = i0 + row;
      if (c < 16)      o_out[gr * 192 + h * 16 + c] = sv;
      else if (c < 40) opt_out[gr * 288 + h * 24 + (c - 16)] = sv;
    }
  } else {
    const int i = blockIdx.x - 576;
    {
#pragma unroll
      for (int itr = 0; itr < 18; itr++) {
        int idx = itr * 256 + t;           // 12*384 = 4608 uints
        int r = idx / 384, c = idx % 384;
        unsigned int v = ((const unsigned int*)(A + (size_t)r * 589824 + (size_t)i * 768))[c];
        unsigned int byteoff = (unsigned int)(r * 1536) + (((unsigned int)(c * 4)) ^ (((unsigned int)(r & 7)) << 4));
        *(unsigned int*)((char*)aL + byteoff) = v;
      }
    }
    __syncthreads();

    f32x4 acc0 = {0.f, 0.f, 0.f, 0.f}, acc1 = acc0;
    const int ar = (lr < 12) ? lr : 0;     // rows 12..15 read row 0; outputs discarded
    const unsigned int rowbase = (unsigned int)(ar * 1536);
    const unsigned int xorv = ((unsigned int)(ar & 7)) << 4;
    const unsigned int lk2 = (unsigned int)(lk * 2);
    const unsigned short* pz0 = pzT + ((size_t)i * 32 + lr) * 768 + lk;
    const unsigned short* pz1 = pzT + ((size_t)i * 32 + 16 + lr) * 768 + lk;
#pragma unroll
    for (int kc = 0; kc < 6; kc++) {
      int k0 = w * 192 + kc * 32;
      unsigned int off = rowbase + (((lk2 + (unsigned int)(k0 * 2))) ^ xorv);
      bf16x8 avf = *(const bf16x8*)((const char*)aL + off);
      bf16x8 b0 = *(const bf16x8*)(pz0 + k0);
      bf16x8 b1 = *(const bf16x8*)(pz1 + k0);
      acc0 = __builtin_amdgcn_mfma_f32_16x16x32_bf16(avf, b0, acc0, 0, 0, 0);
      acc1 = __builtin_amdgcn_mfma_f32_16x16x32_bf16(avf, b1, acc1, 0, 0, 0);
    }
    __syncthreads();   // aL reads done -> reuse as red

#pragma unroll
    for (int r = 0; r < 4; r++) {
      red[(w * 16 + (l >> 4) * 4 + r) * 33 + lr] = acc0[r];
      red[(w * 16 + (l >> 4) * 4 + r) * 33 + 16 + lr] = acc1[r];
    }
    __syncthreads();
    for (int idx = t; idx < 512; idx += 256) {
      int row = idx >> 5, col = idx & 31;
      if (row < 12) {
        float sv = red[(0 * 16 + row) * 33 + col] + red[(1 * 16 + row) * 33 + col] +
                   red[(2 * 16 + row) * 33 + col] + red[(3 * 16 + row) * 33 + col];
        opair_out[i * 384 + row * 32 + col] = sv;
      }
    }
  }
}

// ---------------- kernel D: localize, dists, l1_out, final GEMM ----------------
__global__ __launch_bounds__(512) void kD(
    const float* __restrict__ o_in, const float* __restrict__ opt_in, const float* __restrict__ opair_in,
    const float* __restrict__ rot, const float* __restrict__ trans,
    const float* __restrict__ l1f, const float* __restrict__ Wl1,
    const float* __restrict__ WoutT, const float* __restrict__ bout,
    const float* __restrict__ s_org, float* __restrict__ out) {
  __shared__ float feats[4][960];
  __shared__ float part[2][256][6];
  const int t = threadIdx.x;
  const int n0 = blockIdx.x * 4;

  for (int idx = t; idx < 768; idx += 512) feats[idx / 192][idx % 192] = o_in[n0 * 192 + idx];
  for (int idx = t; idx < 1536; idx += 512) feats[idx / 384][576 + idx % 384] = opair_in[n0 * 384 + idx];
  if (t < 384) {
    int r = t / 96, p = t % 96, n = n0 + r;
    float x = opt_in[n * 288 + p * 3 + 0];
    float y = opt_in[n * 288 + p * 3 + 1];
    float zc = opt_in[n * 288 + p * 3 + 2];
    const float* R = rot + n * 9;
    const float* tr = trans + n * 3;
    float dx = x - tr[0], dy = y - tr[1], dz = zc - tr[2];
    float l0 = R[0] * dx + R[3] * dy + R[6] * dz;
    float l1 = R[1] * dx + R[4] * dy + R[7] * dz;
    float l2 = R[2] * dx + R[5] * dy + R[8] * dz;
    feats[r][192 + p] = l0;
    feats[r][288 + p] = l1;
    feats[r][384 + p] = l2;
    feats[r][480 + p] = sqrtf(l0 * l0 + l1 * l1 + l2 * l2 + 1e-8f);
  } else if (t < 432) {
    int tt = t - 384, r = tt / 12, lq = tt % 12, n = n0 + r;
    int oo = lq / 3, cc = lq % 3;
    float acc = 0.f;
    for (int i = 0; i < 96; i++) acc = fmaf(opt_in[n * 288 + i * 3 + cc], Wl1[i * 4 + oo], acc);
    out[294912 + n * 12 + lq] = l1f[n * 12 + lq] + acc * INV_SQRT96;
  }
  __syncthreads();

  const int fh = t >> 8, tt = t & 255;
  const int o0 = tt & 127, rp = tt >> 7;
  float acc[3][2] = {{0.f, 0.f}, {0.f, 0.f}, {0.f, 0.f}};
  for (int f = fh * 480; f < fh * 480 + 480; f++) {
    float w0 = WoutT[f * 384 + o0];
    float w1 = WoutT[f * 384 + o0 + 128];
    float w2 = WoutT[f * 384 + o0 + 256];
    float s0 = feats[rp * 2][f], s1 = feats[rp * 2 + 1][f];
    acc[0][0] = fmaf(w0, s0, acc[0][0]); acc[0][1] = fmaf(w0, s1, acc[0][1]);
    acc[1][0] = fmaf(w1, s0, acc[1][0]); acc[1][1] = fmaf(w1, s1, acc[1][1]);
    acc[2][0] = fmaf(w2, s0, acc[2][0]); acc[2][1] = fmaf(w2, s1, acc[2][1]);
  }
#pragma unroll
  for (int kq = 0; kq < 3; kq++)
#pragma unroll
    for (int r = 0; r < 2; r++) part[fh][tt][kq * 2 + r] = acc[kq][r];
  __syncthreads();
  if (t < 256) {
    const int ob = t & 127, rb = t >> 7;
#pragma unroll
    for (int kq = 0; kq < 3; kq++) {
      int o = ob + kq * 128;
#pragma unroll
      for (int r = 0; r < 2; r++) {
        int n = n0 + rb * 2 + r;
        float v = part[0][t][kq * 2 + r] + part[1][t][kq * 2 + r] + bout[o] + s_org[n * 384 + o];
        out[n * 384 + o] = v;
      }
    }
  }
}

extern "C" void kernel_launch(void* const* d_in, const int* in_sizes, int n_in,
                              void* d_out, int out_size, void* d_ws, size_t ws_size,
                              hipStream_t stream) {
  (void)in_sizes; (void)n_in; (void)out_size; (void)ws_size;
  const float* s     = (const float*)d_in[0];
  const float* z     = (const float*)d_in[1];
  const float* l1f   = (const float*)d_in[2];
  const float* rot   = (const float*)d_in[3];
  const float* trans = (const float*)d_in[4];
  const float* mask  = (const float*)d_in[5];
  const float* Wq    = (const float*)d_in[6];
  const float* bq    = (const float*)d_in[7];
  const float* Wkv   = (const float*)d_in[8];
  const float* bkv   = (const float*)d_in[9];
  const float* Wqp   = (const float*)d_in[10];
  const float* bqp   = (const float*)d_in[11];
  const float* Wkvp  = (const float*)d_in[12];
  const float* bkvp  = (const float*)d_in[13];
  const float* Wb    = (const float*)d_in[14];
  const float* bb    = (const float*)d_in[15];
  const float* Wdz   = (const float*)d_in[16];
  const float* bdz   = (const float*)d_in[17];
  const float* Wout  = (const float*)d_in[18];
  const float* bout  = (const float*)d_in[19];
  const float* Wl1   = (const float*)d_in[20];
  float* out = (float*)d_out;
  float* ws  = (float*)d_ws;

  float* WT    = ws + OFF_WT;
  float* WoutT = ws + OFF_WOT;
  float* bu    = ws + OFF_BU;
  unsigned short* bm16 = (unsigned short*)(ws + OFF_BM);
  unsigned short* Ab   = (unsigned short*)(ws + OFF_A);
  unsigned short* vcT  = (unsigned short*)(ws + OFF_VCT);
  unsigned short* pzTb = (unsigned short*)(ws + OFF_PZ);
  float* ob    = ws + OFF_O;
  float* optb  = ws + OFF_OPT;
  float* opairb= ws + OFF_OPAIR;
  float* zbf   = ws + OFF_ZB;
  unsigned short* Wc = (unsigned short*)(ws + OFF_WC);
  float* biasc = ws + OFF_BC;
  unsigned short* qcb = (unsigned short*)(ws + OFF_QC);
  unsigned short* kcb = (unsigned short*)(ws + OFF_KC);
  float* sqkb = ws + OFF_SQK;

  kT<<<3342, 256, 0, stream>>>(Wq, Wkv, Wqp, Wkvp, Wout, bq, bkv, bqp, bkvp,
                               Wb, bb, Wdz, bdz,
                               WT, WoutT, bu, vcT, zbf, Wc, biasc);
  kA<<<192, 384, 0, stream>>>(s, rot, trans, WT, bu, qcb, kcb, sqkb, vcT);
  kB7<<<9216, 256, 0, stream>>>(z, Wc, biasc, bm16, pzTb);
  kC1M<<<576, 256, 0, stream>>>(qcb, kcb, sqkb, bm16, mask, Ab);
  kC23b<<<1344, 256, 0, stream>>>(Ab, vcT, pzTb, ob, optb, opairb);
  kD<<<192, 512, 0, stream>>>(ob, optb, opairb, rot, trans, l1f, Wl1, WoutT, bout, s, out);
}